// Round 20
// baseline (188.337 us; speedup 1.0000x reference)
//
#include <hip/hip_runtime.h>
#include <math.h>

#define H 60
#define EPSC 0.01f
#define ALPHAC 0.1f

typedef __attribute__((ext_vector_type(8)))  _Float16      f16x8;
typedef __attribute__((ext_vector_type(4)))  float         f32x4;
typedef __attribute__((ext_vector_type(4)))  unsigned int  uint4v;

// ws layout (bytes):
//   [0, 16384)      A1 frags  ushort[8192]  (GEMM1 A: W2 rows,  m=j, k=i; 2 fp16 levels)
//   [16384, 32768)  A2 frags  ushort[8192]  (GEMM2 A: W2T rows, m=i, k=j; 2 fp16 levels)
//   [32768, 33792)  jconst    float4[64]    (b2, Wim2_0, Wim2_1, W3) zero-padded
//   [33792, 34816)  w1b1      float4[64]    (W1_0, W1_1, b1, 0); i>=60: (0,0,-100,0)
//   [34816, 34820)  h0        float
#define WS_A2_US   8192
#define WS_JC_B    32768
#define WS_WB_B    33792
#define WS_H0_B    34816

// ---------------------------------------------------------------------------
// Prep kernel (unchanged from R16..R19 — verified): 2-level fp16 RNE split of
// W2 in MFMA fragment order for both GEMMs + constant tables + h0.
// Fragment order (16x16x32 f16): frag id f=(sig*4+tile)*2+kt; lane L owns
// element b at [m = 16*tile + (L&15)][k = 32*kt + 8*(L>>4) + b].
// ---------------------------------------------------------------------------
__global__ void dho_prep(const float* __restrict__ Xref, const float* __restrict__ W1,
                         const float* __restrict__ b1, const float* __restrict__ W2,
                         const float* __restrict__ b2, const float* __restrict__ W3,
                         const float* __restrict__ b3, const float* __restrict__ Wim2,
                         const float* __restrict__ Wim3, void* __restrict__ wsv)
{
    unsigned short* A1 = (unsigned short*)wsv;
    unsigned short* A2 = A1 + WS_A2_US;
    float4* jc  = (float4*)((char*)wsv + WS_JC_B);
    float4* wb  = (float4*)((char*)wsv + WS_WB_B);
    float*  h0o = (float*)((char*)wsv + WS_H0_B);
    const int t = threadIdx.x;

    for (int idx = t; idx < 16384; idx += 256) {
        int which = idx >= 8192;
        int rem   = which ? idx - 8192 : idx;
        int fid   = rem >> 9;          // 0..15
        int lane  = (rem >> 3) & 63;
        int b     = rem & 7;
        int sig   = fid >> 3;          // 0..1
        int tile  = (fid >> 1) & 3;
        int kt    = fid & 1;
        int m = 16 * tile + (lane & 15);
        int k = 32 * kt + 8 * (lane >> 4) + b;
        int j = which ? k : m;
        int i = which ? m : k;
        float w = (j < H && i < H) ? W2[j * H + i] : 0.0f;
        _Float16 w0 = (_Float16)w;                 // RNE
        _Float16 w1 = (_Float16)(w - (float)w0);   // RNE of residual
        _Float16 sel = sig ? w1 : w0;
        (which ? A2 : A1)[rem] = __builtin_bit_cast(unsigned short, sel);
    }
    if (t < 64) {
        if (t < H) {
            jc[t] = make_float4(b2[t], Wim2[2 * t], Wim2[2 * t + 1], W3[t]);
            wb[t] = make_float4(W1[2 * t], W1[2 * t + 1], b1[t], 0.0f);
        } else {
            jc[t] = make_float4(0.f, 0.f, 0.f, 0.f);
            wb[t] = make_float4(0.f, 0.f, -100.0f, 0.f);   // softplus(-100)=0, s=0
        }
    }
    __shared__ float z1s[H], z2s[H];
    const float x0 = Xref[0], x1 = Xref[1];
    if (t < H) {
        float a = W1[2 * t] * x0 + W1[2 * t + 1] * x1 + b1[t];
        float e = expf(-fabsf(a));
        z1s[t] = logf(1.0f + e) + fmaxf(a, 0.0f);
    }
    __syncthreads();
    if (t < H) {
        float a = b2[t] + Wim2[2 * t] * x0 + Wim2[2 * t + 1] * x1;
        for (int i2 = 0; i2 < H; ++i2) a += W2[t * H + i2] * z1s[i2];
        float e = expf(-fabsf(a));
        z2s[t] = logf(1.0f + e) + fmaxf(a, 0.0f);
    }
    __syncthreads();
    if (t == 0) {
        float a = b3[0] + Wim3[0] * x0 + Wim3[1] * x1;
        for (int j2 = 0; j2 < H; ++j2) a += W3[j2] * z2s[j2];
        float e = expf(-fabsf(a));
        h0o[0] = logf(1.0f + e) + fmaxf(a, 0.0f);
    }
}

static __device__ __forceinline__ f32x4 mfma16h(uint4v a, uint4v b, f32x4 c) {
    return __builtin_amdgcn_mfma_f32_16x16x32_f16(
        __builtin_bit_cast(f16x8, a), __builtin_bit_cast(f16x8, b), c, 0, 0, 0);
}

// 2-level fp16 split of 8 f32 via v_cvt_pkrtz_f16_f32 (verified R19)
static __device__ __forceinline__ void split2(const float* v, uint4v& f0, uint4v& f1) {
#pragma unroll
    for (int d = 0; d < 4; ++d) {
        float v0 = v[2 * d], v1 = v[2 * d + 1];
        auto h = __builtin_amdgcn_cvt_pkrtz(v0, v1);       // __fp16 x2
        float r0 = v0 - (float)h.x;
        float r1 = v1 - (float)h.y;
        auto hr = __builtin_amdgcn_cvt_pkrtz(r0, r1);
        f0[d] = __builtin_bit_cast(unsigned, h);
        f1[d] = __builtin_bit_cast(unsigned, hr);
    }
}

// sum across lanes {L, L^16, L^32, L^48} (same lane&15)
static __device__ __forceinline__ float redg(float v) {
    v += __shfl_xor(v, 16, 64);
    v += __shfl_xor(v, 32, 64);
    return v;
}

#define TSTR 68   // per-sample stride in floats (16B-aligned, ~2-way banks)

// ---------------------------------------------------------------------------
// Main kernel, R20: R19 + s1 through sbuf (the R13 pattern, single variable).
// z1-gen already computes e1 per element; add rcp+select there and store s1
// to a second per-wave LDS tile; the GEMM2 fold reads it back instead of
// recomputing (kills 16 exp + 16 rcp + ~64 full-rate ops per beta ~ 7% of
// the issue stream). Cost: LDS 50.2 -> 67.6KB -> occupancy 3 -> 2 waves/SIMD.
// Decisive experiment: R10 ran fine at 2 waves (latency-tolerant); if that
// holds here the trim nets -7%, if not the plateau is proven and R19 stands.
// ---------------------------------------------------------------------------
__global__ __launch_bounds__(256, 2) void dho_main(
    const float* __restrict__ X, const float* __restrict__ U,
    const void* __restrict__ wsv,
    const float* __restrict__ W_fnn, const float* __restrict__ W_gnn,
    const float* __restrict__ b_gnn, const float* __restrict__ b3,
    const float* __restrict__ Wim3, const float* __restrict__ Xref,
    float* __restrict__ out, int N)
{
    const float4* jcp = (const float4*)((const char*)wsv + WS_JC_B);
    const float4* wbp = (const float4*)((const char*)wsv + WS_WB_B);
    const float h0 = *(const float*)((const char*)wsv + WS_H0_B);

    __shared__ __align__(16) unsigned short sA[16384];   // A1 ++ A2 = 32 KB
    __shared__ __align__(16) float tbuf[4][16 * TSTR];   // per-wave t transpose
    __shared__ __align__(16) float sbuf[4][16 * TSTR];   // per-wave s1 transpose

    const int tid = threadIdx.x;
    {
        const uint4v* src = (const uint4v*)wsv;
        uint4v* dst = (uint4v*)sA;
#pragma unroll 1
        for (int k = tid; k < 2048; k += 256) dst[k] = src[k];
    }
    __syncthreads();

    const uint4v* fA1 = (const uint4v*)sA;            // 1024 frags
    const uint4v* fA2 = ((const uint4v*)sA) + 1024;

    const int w  = tid >> 6;
    const int L  = tid & 63;
    const int g  = L >> 4;
    const int lm = L & 15;
    const int base = blockIdx.x * 256 + w * 64;
    float* tb = &tbuf[w][0];
    float* sb = &sbuf[w][0];

    const float xr0 = Xref[0], xr1 = Xref[1];
    const float wim3_0 = Wim3[0], wim3_1 = Wim3[1];
    const float b3v = b3[0];
    const float fn0 = W_fnn[0], fn1 = W_fnn[1], fn2 = W_fnn[2], fn3 = W_fnn[3];
    const float gn0 = W_gnn[0], gn1 = W_gnn[1], gn2 = W_gnn[2], gn3 = W_gnn[3];
    const float bg0 = b_gnn[0], bg1 = b_gnn[1];

#pragma unroll 1
    for (int beta = 0; beta < 4; ++beta) {
        const int sid = base + 16 * beta + lm;
        const int sc  = sid < N ? sid : N - 1;
        const float2 x = ((const float2*)X)[sc];
        const float  u = U[sc];

        // ---- z1 + s1 for this batch (s1 -> sbuf; pad-bias: s1(pad)=0) ----
        uint4v Zf[2][2];
#pragma unroll
        for (int kt = 0; kt < 2; ++kt) {
            float zv[8], s1v[8];
#pragma unroll
            for (int b = 0; b < 8; ++b) {
                int i = 32 * kt + 8 * g + b;
                float4 wv = wbp[i];
                float a1 = fmaf(wv.x, x.x, fmaf(wv.y, x.y, wv.z));
                float e1 = __expf(-fabsf(a1));
                float inv = __builtin_amdgcn_rcpf(1.0f + e1);
                zv[b]  = __logf(1.0f + e1) + fmaxf(a1, 0.0f);
                s1v[b] = (a1 >= 0.0f ? 1.0f : e1) * inv;   // pads: e1~0 -> s1~0
            }
            split2(zv, Zf[0][kt], Zf[1][kt]);
            *(float4*)&sb[lm * TSTR + 32 * kt + 8 * g]     = *(float4*)&s1v[0];
            *(float4*)&sb[lm * TSTR + 32 * kt + 8 * g + 4] = *(float4*)&s1v[4];
        }

        // ---- GEMM1 + softplus block (6-product fp16, frags from LDS) ----
        float a3p = 0.0f, q0p = 0.0f, q1p = 0.0f;
#pragma unroll 1
        for (int jt = 0; jt < 4; ++jt) {
            uint4v A00 = fA1[(     jt * 2    ) * 64 + L];
            uint4v A01 = fA1[(     jt * 2 + 1) * 64 + L];
            uint4v A10 = fA1[(8 +  jt * 2    ) * 64 + L];
            uint4v A11 = fA1[(8 +  jt * 2 + 1) * 64 + L];
            f32x4 acc0 = {0.f, 0.f, 0.f, 0.f};
            f32x4 acc1 = {0.f, 0.f, 0.f, 0.f};
            acc0 = mfma16h(A00, Zf[0][0], acc0);
            acc1 = mfma16h(A01, Zf[0][1], acc1);
            acc0 = mfma16h(A00, Zf[1][0], acc0);
            acc1 = mfma16h(A01, Zf[1][1], acc1);
            acc0 = mfma16h(A10, Zf[0][0], acc0);
            acc1 = mfma16h(A11, Zf[0][1], acc1);
            // w1*z1 term dropped (<= 2^-22 rel)
            f32x4 acc = acc0 + acc1;

            float4 tq;
#pragma unroll
            for (int r = 0; r < 4; ++r) {
                int j = 16 * jt + 4 * g + r;
                float4 jc = jcp[j];
                float a2 = acc[r] + jc.x + jc.y * x.x + jc.z * x.y;
                float e = __expf(-fabsf(a2));
                float inv = __builtin_amdgcn_rcpf(1.0f + e);
                float z2 = __logf(1.0f + e) + fmaxf(a2, 0.0f);
                float s2 = (a2 >= 0.0f ? 1.0f : e) * inv;
                a3p = fmaf(jc.w, z2, a3p);
                float tv = jc.w * s2;
                q0p = fmaf(tv, jc.y, q0p);
                q1p = fmaf(tv, jc.z, q1p);
                ((float*)&tq)[r] = tv;
            }
            *(float4*)&tb[lm * TSTR + 16 * jt + 4 * g] = tq;
        }

        // ---- output layer + sigma ----
        float a3 = redg(a3p) + b3v + wim3_0 * x.x + wim3_1 * x.y;
        float qa = wim3_0 + redg(q0p);
        float qb = wim3_1 + redg(q1p);
        float e3 = __expf(-fabsf(a3));
        float inv3 = __builtin_amdgcn_rcpf(1.0f + e3);
        float hX = __logf(1.0f + e3) + fmaxf(a3, 0.0f);
        float s3 = (a3 >= 0.0f ? 1.0f : e3) * inv3;
        float h = hX - h0;
        float sigma, sigp;
        if (h >= 1.0f)      { sigma = h - 0.5f;      sigp = 1.0f; }
        else if (h > 0.0f)  { sigma = 0.5f * h * h;  sigp = h; }
        else                { sigma = 0.0f;          sigp = 0.0f; }
        float dx0 = x.x - xr0, dx1 = x.y - xr1;
        float V = sigma + EPSC * (dx0 * dx0 + dx1 * dx1);

        // ---- t fragments (same-wave LDS transpose) ----
        uint4v Tf[2][2];
#pragma unroll
        for (int kt = 0; kt < 2; ++kt) {
            float tv[8];
            *(float4*)&tv[0] = *(const float4*)&tb[lm * TSTR + 32 * kt + 8 * g];
            *(float4*)&tv[4] = *(const float4*)&tb[lm * TSTR + 32 * kt + 8 * g + 4];
            split2(tv, Tf[0][kt], Tf[1][kt]);
        }

        // ---- GEMM2 + layer-1 backprop fold (s1 from sbuf, no recompute) ----
        float p0 = 0.0f, p1 = 0.0f;
#pragma unroll 1
        for (int it = 0; it < 4; ++it) {
            uint4v A00 = fA2[(     it * 2    ) * 64 + L];
            uint4v A01 = fA2[(     it * 2 + 1) * 64 + L];
            uint4v A10 = fA2[(8 +  it * 2    ) * 64 + L];
            uint4v A11 = fA2[(8 +  it * 2 + 1) * 64 + L];
            f32x4 acc0 = {0.f, 0.f, 0.f, 0.f};
            f32x4 acc1 = {0.f, 0.f, 0.f, 0.f};
            acc0 = mfma16h(A00, Tf[0][0], acc0);
            acc1 = mfma16h(A01, Tf[0][1], acc1);
            acc0 = mfma16h(A00, Tf[1][0], acc0);
            acc1 = mfma16h(A01, Tf[1][1], acc1);
            acc0 = mfma16h(A10, Tf[0][0], acc0);
            acc1 = mfma16h(A11, Tf[0][1], acc1);
            // w1*t1 term dropped (<= 2^-22 rel)
            f32x4 acc = acc0 + acc1;

            float4 s1q = *(const float4*)&sb[lm * TSTR + 16 * it + 4 * g];
#pragma unroll
            for (int r = 0; r < 4; ++r) {
                int i = 16 * it + 4 * g + r;
                float4 wv = wbp[i];
                float c = acc[r] * ((const float*)&s1q)[r];   // pads: s1~0 -> c~0
                p0 = fmaf(c, wv.x, p0);
                p1 = fmaf(c, wv.y, p1);
            }
        }
        float sum0 = redg(p0), sum1 = redg(p1);

        // ---- epilogue ----
        float dh0 = s3 * (qa + sum0);
        float dh1 = s3 * (qb + sum1);
        float dV0 = sigp * dh0 + 2.0f * EPSC * dx0;
        float dV1 = sigp * dh1 + 2.0f * EPSC * dx1;
        float f0 = fn0 * x.x + fn1 * x.y;
        float f1 = fn2 * x.x + fn3 * x.y;
        float gg0 = gn0 * x.x + gn1 * x.y + bg0;
        float gg1 = gn2 * x.x + gn3 * x.y + bg1;
        float scv = dV0 * f0 + dV1 * f1 + ALPHAC * V - fabsf(dV0 * gg0 + dV1 * gg1);
        float nrm = dV0 * dV0 + dV1 * dV1;
        float rr = fmaxf(scv, 0.0f) * __builtin_amdgcn_rcpf(nrm);
        float o0 = f0 - dV0 * rr + gg0 * u;
        float o1 = f1 - dV1 * rr + gg1 * u;
        if (g == 0 && sid < N) ((float2*)out)[sid] = make_float2(o0, o1);

        __builtin_amdgcn_sched_barrier(0);   // no cross-beta hoisting
    }
}

extern "C" void kernel_launch(void* const* d_in, const int* in_sizes, int n_in,
                              void* d_out, int out_size, void* d_ws, size_t ws_size,
                              hipStream_t stream) {
    // 0:X 1:U 2:Xref 3:W_fnn 4:W_gnn 5:b_gnn 6:W1 7:b1 8:W2 9:b2 10:W3 11:b3 12:Wim2 13:Wim3
    const float* X     = (const float*)d_in[0];
    const float* U     = (const float*)d_in[1];
    const float* Xref  = (const float*)d_in[2];
    const float* W_fnn = (const float*)d_in[3];
    const float* W_gnn = (const float*)d_in[4];
    const float* b_gnn = (const float*)d_in[5];
    const float* W1    = (const float*)d_in[6];
    const float* b1    = (const float*)d_in[7];
    const float* W2    = (const float*)d_in[8];
    const float* b2    = (const float*)d_in[9];
    const float* W3    = (const float*)d_in[10];
    const float* b3    = (const float*)d_in[11];
    const float* Wim2  = (const float*)d_in[12];
    const float* Wim3  = (const float*)d_in[13];

    const int N = in_sizes[0] / 2;
    float* outp = (float*)d_out;

    dho_prep<<<1, 256, 0, stream>>>(Xref, W1, b1, W2, b2, W3, b3, Wim2, Wim3, d_ws);

    const int blocks = (N + 255) / 256;
    dho_main<<<blocks, 256, 0, stream>>>(
        X, U, d_ws, W_fnn, W_gnn, b_gnn, b3, Wim3, Xref, outp, N);
}

// Round 21
// 177.017 us; speedup vs baseline: 1.0640x; 1.0640x over previous
//
#include <hip/hip_runtime.h>
#include <math.h>

#define H 60
#define EPSC 0.01f
#define ALPHAC 0.1f

typedef __attribute__((ext_vector_type(8)))  _Float16      f16x8;
typedef __attribute__((ext_vector_type(4)))  float         f32x4;
typedef __attribute__((ext_vector_type(4)))  unsigned int  uint4v;

// ws layout (bytes):
//   [0, 16384)      A1 frags  ushort[8192]  (GEMM1 A: W2 rows,  m=j, k=i; 2 fp16 levels)
//   [16384, 32768)  A2 frags  ushort[8192]  (GEMM2 A: W2T rows, m=i, k=j; 2 fp16 levels)
//   [32768, 33792)  jconst    float4[64]    (b2, Wim2_0, Wim2_1, W3) zero-padded
//   [33792, 34816)  w1b1      float4[64]    (W1_0, W1_1, b1, 0); i>=60: (0,0,-100,0)
//   [34816, 34820)  h0        float
#define WS_A2_US   8192
#define WS_JC_B    32768
#define WS_WB_B    33792
#define WS_H0_B    34816

// ---------------------------------------------------------------------------
// Prep kernel (verified R16..R19): 2-level fp16 RNE split of W2 in MFMA
// fragment order for both GEMMs + constant tables + h0.
// Fragment order (16x16x32 f16): frag id f=(sig*4+tile)*2+kt; lane L owns
// element b at [m = 16*tile + (L&15)][k = 32*kt + 8*(L>>4) + b].
// ---------------------------------------------------------------------------
__global__ void dho_prep(const float* __restrict__ Xref, const float* __restrict__ W1,
                         const float* __restrict__ b1, const float* __restrict__ W2,
                         const float* __restrict__ b2, const float* __restrict__ W3,
                         const float* __restrict__ b3, const float* __restrict__ Wim2,
                         const float* __restrict__ Wim3, void* __restrict__ wsv)
{
    unsigned short* A1 = (unsigned short*)wsv;
    unsigned short* A2 = A1 + WS_A2_US;
    float4* jc  = (float4*)((char*)wsv + WS_JC_B);
    float4* wb  = (float4*)((char*)wsv + WS_WB_B);
    float*  h0o = (float*)((char*)wsv + WS_H0_B);
    const int t = threadIdx.x;

    for (int idx = t; idx < 16384; idx += 256) {
        int which = idx >= 8192;
        int rem   = which ? idx - 8192 : idx;
        int fid   = rem >> 9;          // 0..15
        int lane  = (rem >> 3) & 63;
        int b     = rem & 7;
        int sig   = fid >> 3;          // 0..1
        int tile  = (fid >> 1) & 3;
        int kt    = fid & 1;
        int m = 16 * tile + (lane & 15);
        int k = 32 * kt + 8 * (lane >> 4) + b;
        int j = which ? k : m;
        int i = which ? m : k;
        float w = (j < H && i < H) ? W2[j * H + i] : 0.0f;
        _Float16 w0 = (_Float16)w;                 // RNE
        _Float16 w1 = (_Float16)(w - (float)w0);   // RNE of residual
        _Float16 sel = sig ? w1 : w0;
        (which ? A2 : A1)[rem] = __builtin_bit_cast(unsigned short, sel);
    }
    if (t < 64) {
        if (t < H) {
            jc[t] = make_float4(b2[t], Wim2[2 * t], Wim2[2 * t + 1], W3[t]);
            wb[t] = make_float4(W1[2 * t], W1[2 * t + 1], b1[t], 0.0f);
        } else {
            jc[t] = make_float4(0.f, 0.f, 0.f, 0.f);
            wb[t] = make_float4(0.f, 0.f, -100.0f, 0.f);   // softplus(-100)=0, s=0
        }
    }
    __shared__ float z1s[H], z2s[H];
    const float x0 = Xref[0], x1 = Xref[1];
    if (t < H) {
        float a = W1[2 * t] * x0 + W1[2 * t + 1] * x1 + b1[t];
        float e = expf(-fabsf(a));
        z1s[t] = logf(1.0f + e) + fmaxf(a, 0.0f);
    }
    __syncthreads();
    if (t < H) {
        float a = b2[t] + Wim2[2 * t] * x0 + Wim2[2 * t + 1] * x1;
        for (int i2 = 0; i2 < H; ++i2) a += W2[t * H + i2] * z1s[i2];
        float e = expf(-fabsf(a));
        z2s[t] = logf(1.0f + e) + fmaxf(a, 0.0f);
    }
    __syncthreads();
    if (t == 0) {
        float a = b3[0] + Wim3[0] * x0 + Wim3[1] * x1;
        for (int j2 = 0; j2 < H; ++j2) a += W3[j2] * z2s[j2];
        float e = expf(-fabsf(a));
        h0o[0] = logf(1.0f + e) + fmaxf(a, 0.0f);
    }
}

static __device__ __forceinline__ f32x4 mfma16h(uint4v a, uint4v b, f32x4 c) {
    return __builtin_amdgcn_mfma_f32_16x16x32_f16(
        __builtin_bit_cast(f16x8, a), __builtin_bit_cast(f16x8, b), c, 0, 0, 0);
}

// 2-level fp16 split of 8 f32 via v_cvt_pkrtz_f16_f32 (verified R19)
static __device__ __forceinline__ void split2(const float* v, uint4v& f0, uint4v& f1) {
#pragma unroll
    for (int d = 0; d < 4; ++d) {
        float v0 = v[2 * d], v1 = v[2 * d + 1];
        auto h = __builtin_amdgcn_cvt_pkrtz(v0, v1);       // __fp16 x2
        float r0 = v0 - (float)h.x;
        float r1 = v1 - (float)h.y;
        auto hr = __builtin_amdgcn_cvt_pkrtz(r0, r1);
        f0[d] = __builtin_bit_cast(unsigned, h);
        f1[d] = __builtin_bit_cast(unsigned, hr);
    }
}

// sum across lanes {L, L^16, L^32, L^48} (same lane&15)
static __device__ __forceinline__ float redg(float v) {
    v += __shfl_xor(v, 16, 64);
    v += __shfl_xor(v, 32, 64);
    return v;
}

#define TSTR 68   // per-sample stride in floats (16B-aligned, ~2-way banks)

// ---------------------------------------------------------------------------
// Main kernel, R21 = R19 reverted (best verified: 177.6us, absmax 0.0078125).
// R20's s1-sbuf trade regressed (occupancy 3->2 waves/SIMD cost more than the
// instruction savings: VALUBusy 82->70, dur 178->188) — proving 3 waves/SIMD
// at 50.2KB LDS is the operating point. The kernel is VALU-issue-bound at
// ~82% busy; all >3% levers tested across R10-R20 (occupancy both ways,
// LDS-vs-L2 frags, pipelining, split arithmetic/packing, s1 placement).
// ---------------------------------------------------------------------------
__global__ __launch_bounds__(256, 3) void dho_main(
    const float* __restrict__ X, const float* __restrict__ U,
    const void* __restrict__ wsv,
    const float* __restrict__ W_fnn, const float* __restrict__ W_gnn,
    const float* __restrict__ b_gnn, const float* __restrict__ b3,
    const float* __restrict__ Wim3, const float* __restrict__ Xref,
    float* __restrict__ out, int N)
{
    const float4* jcp = (const float4*)((const char*)wsv + WS_JC_B);
    const float4* wbp = (const float4*)((const char*)wsv + WS_WB_B);
    const float h0 = *(const float*)((const char*)wsv + WS_H0_B);

    __shared__ __align__(16) unsigned short sA[16384];   // A1 ++ A2 = 32 KB
    __shared__ __align__(16) float tbuf[4][16 * TSTR];   // per-wave t transpose

    const int tid = threadIdx.x;
    {
        const uint4v* src = (const uint4v*)wsv;
        uint4v* dst = (uint4v*)sA;
#pragma unroll 1
        for (int k = tid; k < 2048; k += 256) dst[k] = src[k];
    }
    __syncthreads();

    const uint4v* fA1 = (const uint4v*)sA;            // 1024 frags
    const uint4v* fA2 = ((const uint4v*)sA) + 1024;

    const int w  = tid >> 6;
    const int L  = tid & 63;
    const int g  = L >> 4;
    const int lm = L & 15;
    const int base = blockIdx.x * 256 + w * 64;
    float* tb = &tbuf[w][0];

    const float xr0 = Xref[0], xr1 = Xref[1];
    const float wim3_0 = Wim3[0], wim3_1 = Wim3[1];
    const float b3v = b3[0];
    const float fn0 = W_fnn[0], fn1 = W_fnn[1], fn2 = W_fnn[2], fn3 = W_fnn[3];
    const float gn0 = W_gnn[0], gn1 = W_gnn[1], gn2 = W_gnn[2], gn3 = W_gnn[3];
    const float bg0 = b_gnn[0], bg1 = b_gnn[1];

#pragma unroll 1
    for (int beta = 0; beta < 4; ++beta) {
        const int sid = base + 16 * beta + lm;
        const int sc  = sid < N ? sid : N - 1;
        const float2 x = ((const float2*)X)[sc];
        const float  u = U[sc];

        // ---- z1 fragments for this batch (pad-bias: no selects) ----
        uint4v Zf[2][2];
#pragma unroll
        for (int kt = 0; kt < 2; ++kt) {
            float zv[8];
#pragma unroll
            for (int b = 0; b < 8; ++b) {
                int i = 32 * kt + 8 * g + b;
                float4 wv = wbp[i];
                float a1 = fmaf(wv.x, x.x, fmaf(wv.y, x.y, wv.z));
                float e1 = __expf(-fabsf(a1));
                zv[b] = __logf(1.0f + e1) + fmaxf(a1, 0.0f);
            }
            split2(zv, Zf[0][kt], Zf[1][kt]);
        }

        // ---- GEMM1 + softplus block (6-product fp16, frags from LDS) ----
        float a3p = 0.0f, q0p = 0.0f, q1p = 0.0f;
#pragma unroll 1
        for (int jt = 0; jt < 4; ++jt) {
            uint4v A00 = fA1[(     jt * 2    ) * 64 + L];
            uint4v A01 = fA1[(     jt * 2 + 1) * 64 + L];
            uint4v A10 = fA1[(8 +  jt * 2    ) * 64 + L];
            uint4v A11 = fA1[(8 +  jt * 2 + 1) * 64 + L];
            f32x4 acc0 = {0.f, 0.f, 0.f, 0.f};
            f32x4 acc1 = {0.f, 0.f, 0.f, 0.f};
            acc0 = mfma16h(A00, Zf[0][0], acc0);
            acc1 = mfma16h(A01, Zf[0][1], acc1);
            acc0 = mfma16h(A00, Zf[1][0], acc0);
            acc1 = mfma16h(A01, Zf[1][1], acc1);
            acc0 = mfma16h(A10, Zf[0][0], acc0);
            acc1 = mfma16h(A11, Zf[0][1], acc1);
            // w1*z1 term dropped (<= 2^-22 rel)
            f32x4 acc = acc0 + acc1;

            float4 tq;
#pragma unroll
            for (int r = 0; r < 4; ++r) {
                int j = 16 * jt + 4 * g + r;
                float4 jc = jcp[j];
                float a2 = acc[r] + jc.x + jc.y * x.x + jc.z * x.y;
                float e = __expf(-fabsf(a2));
                float inv = __builtin_amdgcn_rcpf(1.0f + e);
                float z2 = __logf(1.0f + e) + fmaxf(a2, 0.0f);
                float s2 = (a2 >= 0.0f ? 1.0f : e) * inv;
                a3p = fmaf(jc.w, z2, a3p);
                float tv = jc.w * s2;
                q0p = fmaf(tv, jc.y, q0p);
                q1p = fmaf(tv, jc.z, q1p);
                ((float*)&tq)[r] = tv;
            }
            *(float4*)&tb[lm * TSTR + 16 * jt + 4 * g] = tq;
        }

        // ---- output layer + sigma ----
        float a3 = redg(a3p) + b3v + wim3_0 * x.x + wim3_1 * x.y;
        float qa = wim3_0 + redg(q0p);
        float qb = wim3_1 + redg(q1p);
        float e3 = __expf(-fabsf(a3));
        float inv3 = __builtin_amdgcn_rcpf(1.0f + e3);
        float hX = __logf(1.0f + e3) + fmaxf(a3, 0.0f);
        float s3 = (a3 >= 0.0f ? 1.0f : e3) * inv3;
        float h = hX - h0;
        float sigma, sigp;
        if (h >= 1.0f)      { sigma = h - 0.5f;      sigp = 1.0f; }
        else if (h > 0.0f)  { sigma = 0.5f * h * h;  sigp = h; }
        else                { sigma = 0.0f;          sigp = 0.0f; }
        float dx0 = x.x - xr0, dx1 = x.y - xr1;
        float V = sigma + EPSC * (dx0 * dx0 + dx1 * dx1);

        // ---- t fragments (same-wave LDS transpose) ----
        uint4v Tf[2][2];
#pragma unroll
        for (int kt = 0; kt < 2; ++kt) {
            float tv[8];
            *(float4*)&tv[0] = *(const float4*)&tb[lm * TSTR + 32 * kt + 8 * g];
            *(float4*)&tv[4] = *(const float4*)&tb[lm * TSTR + 32 * kt + 8 * g + 4];
            split2(tv, Tf[0][kt], Tf[1][kt]);
        }

        // ---- GEMM2 + layer-1 backprop fold (s1 recomputed; pads free) ----
        float p0 = 0.0f, p1 = 0.0f;
#pragma unroll 1
        for (int it = 0; it < 4; ++it) {
            uint4v A00 = fA2[(     it * 2    ) * 64 + L];
            uint4v A01 = fA2[(     it * 2 + 1) * 64 + L];
            uint4v A10 = fA2[(8 +  it * 2    ) * 64 + L];
            uint4v A11 = fA2[(8 +  it * 2 + 1) * 64 + L];
            f32x4 acc0 = {0.f, 0.f, 0.f, 0.f};
            f32x4 acc1 = {0.f, 0.f, 0.f, 0.f};
            acc0 = mfma16h(A00, Tf[0][0], acc0);
            acc1 = mfma16h(A01, Tf[0][1], acc1);
            acc0 = mfma16h(A00, Tf[1][0], acc0);
            acc1 = mfma16h(A01, Tf[1][1], acc1);
            acc0 = mfma16h(A10, Tf[0][0], acc0);
            acc1 = mfma16h(A11, Tf[0][1], acc1);
            // w1*t1 term dropped (<= 2^-22 rel)
            f32x4 acc = acc0 + acc1;
#pragma unroll
            for (int r = 0; r < 4; ++r) {
                int i = 16 * it + 4 * g + r;
                float4 wv = wbp[i];
                float a1 = fmaf(wv.x, x.x, fmaf(wv.y, x.y, wv.z));
                float e1 = __expf(-fabsf(a1));
                float s1 = (a1 >= 0.0f ? 1.0f : e1) * __builtin_amdgcn_rcpf(1.0f + e1);
                float c = acc[r] * s1;       // pads: bias -100 -> s1=0 -> c=0
                p0 = fmaf(c, wv.x, p0);
                p1 = fmaf(c, wv.y, p1);
            }
        }
        float sum0 = redg(p0), sum1 = redg(p1);

        // ---- epilogue ----
        float dh0 = s3 * (qa + sum0);
        float dh1 = s3 * (qb + sum1);
        float dV0 = sigp * dh0 + 2.0f * EPSC * dx0;
        float dV1 = sigp * dh1 + 2.0f * EPSC * dx1;
        float f0 = fn0 * x.x + fn1 * x.y;
        float f1 = fn2 * x.x + fn3 * x.y;
        float gg0 = gn0 * x.x + gn1 * x.y + bg0;
        float gg1 = gn2 * x.x + gn3 * x.y + bg1;
        float scv = dV0 * f0 + dV1 * f1 + ALPHAC * V - fabsf(dV0 * gg0 + dV1 * gg1);
        float nrm = dV0 * dV0 + dV1 * dV1;
        float rr = fmaxf(scv, 0.0f) * __builtin_amdgcn_rcpf(nrm);
        float o0 = f0 - dV0 * rr + gg0 * u;
        float o1 = f1 - dV1 * rr + gg1 * u;
        if (g == 0 && sid < N) ((float2*)out)[sid] = make_float2(o0, o1);

        __builtin_amdgcn_sched_barrier(0);   // no cross-beta hoisting
    }
}

extern "C" void kernel_launch(void* const* d_in, const int* in_sizes, int n_in,
                              void* d_out, int out_size, void* d_ws, size_t ws_size,
                              hipStream_t stream) {
    // 0:X 1:U 2:Xref 3:W_fnn 4:W_gnn 5:b_gnn 6:W1 7:b1 8:W2 9:b2 10:W3 11:b3 12:Wim2 13:Wim3
    const float* X     = (const float*)d_in[0];
    const float* U     = (const float*)d_in[1];
    const float* Xref  = (const float*)d_in[2];
    const float* W_fnn = (const float*)d_in[3];
    const float* W_gnn = (const float*)d_in[4];
    const float* b_gnn = (const float*)d_in[5];
    const float* W1    = (const float*)d_in[6];
    const float* b1    = (const float*)d_in[7];
    const float* W2    = (const float*)d_in[8];
    const float* b2    = (const float*)d_in[9];
    const float* W3    = (const float*)d_in[10];
    const float* b3    = (const float*)d_in[11];
    const float* Wim2  = (const float*)d_in[12];
    const float* Wim3  = (const float*)d_in[13];

    const int N = in_sizes[0] / 2;
    float* outp = (float*)d_out;

    dho_prep<<<1, 256, 0, stream>>>(Xref, W1, b1, W2, b2, W3, b3, Wim2, Wim3, d_ws);

    const int blocks = (N + 255) / 256;
    dho_main<<<blocks, 256, 0, stream>>>(
        X, U, d_ws, W_fnn, W_gnn, b_gnn, b3, Wim3, Xref, outp, N);
}